// Round 1
// baseline (2618.838 us; speedup 1.0000x reference)
//
#include <hip/hip_runtime.h>

// Billeh column GLIF forward — single persistent kernel.
// Neuron state lives in registers for all T steps; spikes cross threads via a
// 12.5KB global bitmask; grid-wide ordering via a hand-rolled monotonic
// atomic barrier (196 co-resident blocks, guaranteed by __launch_bounds__).
// Steps with zero spikes skip the scatter phase AND its barrier.

constexpr int RR = 4;

// ---------------- one-time: zero barrier counter + per-step spike flags ----
__global__ void init_kernel(unsigned int* __restrict__ bar,
                            int* __restrict__ any_arr, int T) {
    if (threadIdx.x == 0) *bar = 0u;
    for (int t = threadIdx.x; t < T; t += blockDim.x) any_arr[t] = 0;
}

// Monotonic grid barrier. Counter zeroed per launch by init_kernel; target is
// epoch * gridDim.x. Leader does device-scope release (wb L2) before arrive and
// device-scope acquire (inv L1/L2) after — same semantics a kernel boundary
// provides, which the previous multi-kernel version already relied on.
__device__ __forceinline__ void grid_barrier(unsigned int* cnt, unsigned int target) {
    __syncthreads();
    if (threadIdx.x == 0) {
        __threadfence();
        __hip_atomic_fetch_add(cnt, 1u, __ATOMIC_RELEASE, __HIP_MEMORY_SCOPE_AGENT);
        while (__hip_atomic_load(cnt, __ATOMIC_ACQUIRE, __HIP_MEMORY_SCOPE_AGENT) < target)
            __builtin_amdgcn_s_sleep(1);
        __threadfence();
    }
    __syncthreads();
}

__global__ void __launch_bounds__(512, 2)
sim_kernel(const float* __restrict__ w_rec,
           const float* __restrict__ x_ext,
           const float* __restrict__ v0,
           const float* __restrict__ v_th,
           const float* __restrict__ v_rst,
           const float* __restrict__ t_rf,
           const float* __restrict__ decay,
           const float* __restrict__ curf,
           const float* __restrict__ e_l,
           const float2* __restrict__ aamps,
           const float2* __restrict__ adec,
           const float* __restrict__ syn_d,
           const float* __restrict__ psc_i,
           const int* __restrict__ pre,
           const int* __restrict__ post,
           const int* __restrict__ rc,
           float* __restrict__ rec_in,
           unsigned long long* __restrict__ mask,
           int* __restrict__ any_arr,
           unsigned int* __restrict__ bar,
           float* __restrict__ out,
           int E, int N, int T)
{
    const int gtid = blockIdx.x * blockDim.x + threadIdx.x;
    const int nth  = gridDim.x * blockDim.x;
    const bool own = gtid < N;

    // ---- per-neuron state + params: registers for the whole simulation ----
    float psc0 = 0.f, psc1 = 0.f, psc2 = 0.f, psc3 = 0.f;
    float pr0 = 0.f, pr1 = 0.f, pr2 = 0.f, pr3 = 0.f;
    float vv = 0.f, rr = 0.f, zz = 0.f, a0 = 0.f, a1 = 0.f;
    float vth = 1.f, vrst = 0.f, trf = 0.f, dec = 0.f, cf = 0.f, el = 0.f;
    float aa0 = 0.f, aa1 = 0.f, ad0 = 0.f, ad1 = 0.f;
    if (own) {
        vv   = v0[gtid];
        vth  = v_th[gtid];  vrst = v_rst[gtid];
        trf  = t_rf[gtid];  dec  = decay[gtid];
        cf   = curf[gtid];  el   = e_l[gtid];
        float2 aa = aamps[gtid]; aa0 = aa.x; aa1 = aa.y;
        float2 ad = adec[gtid];  ad0 = ad.x; ad1 = ad.y;
        ((float4*)rec_in)[gtid] = make_float4(0.f, 0.f, 0.f, 0.f);
    }
    // wave-uniform -> scalar regs
    const float sd0 = syn_d[0], sd1 = syn_d[1], sd2 = syn_d[2], sd3 = syn_d[3];
    const float pi0 = psc_i[0], pi1 = psc_i[1], pi2 = psc_i[2], pi3 = psc_i[3];

    const int E4 = E >> 2;
    const int tailbase = E & ~3;
    unsigned int epoch = 0;

    for (int t = 0; t < T; ++t) {
        // ---------------- scatter phase (only if last step spiked) ---------
        bool had = false;
        if (t > 0) {
            had = (any_arr[t - 1] != 0);        // uniform: read after barrier
            if (had) {
                for (int q = gtid; q < E4; q += nth) {
                    const int e0 = q << 2;
                    int4 p = *(const int4*)(pre + e0);
                    bool b0 = (mask[p.x >> 6] >> (p.x & 63)) & 1ull;
                    bool b1 = (mask[p.y >> 6] >> (p.y & 63)) & 1ull;
                    bool b2 = (mask[p.z >> 6] >> (p.z & 63)) & 1ull;
                    bool b3 = (mask[p.w >> 6] >> (p.w & 63)) & 1ull;
                    if (b0 | b1 | b2 | b3) {
                        int4 po = *(const int4*)(post + e0);
                        int4 rc4 = *(const int4*)(rc + e0);
                        float4 ww = *(const float4*)(w_rec + e0);
                        if (b0) atomicAdd(rec_in + po.x * RR + rc4.x, ww.x);
                        if (b1) atomicAdd(rec_in + po.y * RR + rc4.y, ww.y);
                        if (b2) atomicAdd(rec_in + po.z * RR + rc4.z, ww.z);
                        if (b3) atomicAdd(rec_in + po.w * RR + rc4.w, ww.w);
                    }
                }
                for (int e = tailbase + gtid; e < E; e += nth) {
                    int p = pre[e];
                    if ((mask[p >> 6] >> (p & 63)) & 1ull)
                        atomicAdd(rec_in + post[e] * RR + rc[e], w_rec[e]);
                }
                ++epoch;
                grid_barrier(bar, epoch * gridDim.x);
            }
        }

        // ---------------- neuron update (all state in registers) -----------
        float nz = 0.f;
        if (own) {
            float4 ri = had ? ((float4*)rec_in)[gtid]
                            : make_float4(0.f, 0.f, 0.f, 0.f);
            float4 xt = ((const float4*)x_ext)[(size_t)t * N + gtid];
            if (had)  // restore the all-zero invariant for the next scatter
                ((float4*)rec_in)[gtid] = make_float4(0.f, 0.f, 0.f, 0.f);

            float i0 = ri.x + xt.x, i1 = ri.y + xt.y;
            float i2 = ri.z + xt.z, i3 = ri.w + xt.w;
            float npr0 = pr0 * sd0 + i0 * pi0;
            float npr1 = pr1 * sd1 + i1 * pi1;
            float npr2 = pr2 * sd2 + i2 * pi2;
            float npr3 = pr3 * sd3 + i3 * pi3;
            float npc0 = psc0 * sd0 + sd0 * pr0;   // uses OLD psc_rise, DT=1
            float npc1 = psc1 * sd1 + sd1 * pr1;
            float npc2 = psc2 * sd2 + sd2 * pr2;
            float npc3 = psc3 * sd3 + sd3 * pr3;
            float in_cur = npc0 + npc1 + npc2 + npc3;
            psc0 = npc0; psc1 = npc1; psc2 = npc2; psc3 = npc3;
            pr0 = npr0; pr1 = npr1; pr2 = npr2; pr3 = npr3;

            float asum = a0 + a1;                  // OLD asc sum
            a0 = ad0 * a0 + zz * aa0;
            a1 = ad1 * a1 + zz * aa1;

            float nv  = dec * vv + cf * (in_cur + asum + el) + zz * (vrst - vth);
            float vsc = (nv - vth) / vth;
            nz = (vsc > 0.f) ? 1.f : 0.f;
            if (rr > 0.f) nz = 0.f;                // refractory mask (OLD r)
            rr = fmaxf(rr - 1.f + nz * trf, 0.f);
            vv = nv; zz = nz;
            out[(size_t)t * N + gtid] = nz;
        }

        // publish spike bitmask + "anything spiked" flag
        unsigned long long bal = __ballot(nz > 0.f);
        if (own && (gtid & 63) == 0) mask[gtid >> 6] = bal;
        if (bal != 0ull && (gtid & 63) == 0) any_arr[t] = 1;

        if (t != T - 1) {
            ++epoch;
            grid_barrier(bar, epoch * gridDim.x);
        }
    }
}

extern "C" void kernel_launch(void* const* d_in, const int* in_sizes, int n_in,
                              void* d_out, int out_size, void* d_ws, size_t ws_size,
                              hipStream_t stream) {
    const float* w_rec = (const float*)d_in[0];
    const float* x_ext = (const float*)d_in[1];
    const float* v0    = (const float*)d_in[2];
    const float* v_th  = (const float*)d_in[3];
    const float* v_rst = (const float*)d_in[4];
    const float* t_rf  = (const float*)d_in[5];
    const float* decay = (const float*)d_in[6];
    const float* curf  = (const float*)d_in[7];
    const float* e_l   = (const float*)d_in[8];
    const float* aamps = (const float*)d_in[9];
    const float* adec  = (const float*)d_in[10];
    const float* syn_d = (const float*)d_in[11];
    const float* psc_i = (const float*)d_in[12];
    const int*   pre   = (const int*)d_in[13];
    const int*   post  = (const int*)d_in[14];
    const int*   rc    = (const int*)d_in[15];

    const int E = in_sizes[0];
    const int N = in_sizes[2];            // B == 1
    const int T = in_sizes[1] / (N * RR);

    // -------- workspace layout --------
    float* wf = (float*)d_ws;
    float* rec_in = wf;                                        // 4N floats
    const int nwords = (N + 63) / 64;
    unsigned long long* mask = (unsigned long long*)(wf + (size_t)4 * N); // 16N B offset, 8B-aligned
    int* any_arr = (int*)(mask + nwords);                      // T ints
    unsigned int* bar = (unsigned int*)(any_arr + T);          // 1 word

    init_kernel<<<1, 256, 0, stream>>>(bar, any_arr, T);

    const int BS = 512;
    const int nblk = (N + BS - 1) / BS;   // 196 blocks @ N=100000 -> 1 block/CU,
                                          // co-residency guaranteed by
                                          // __launch_bounds__(512,2) (<=256 VGPR)
    sim_kernel<<<nblk, BS, 0, stream>>>(
        w_rec, x_ext, v0, v_th, v_rst, t_rf, decay, curf, e_l,
        (const float2*)aamps, (const float2*)adec, syn_d, psc_i,
        pre, post, rc, rec_in, mask, any_arr, bar,
        (float*)d_out, E, N, T);
}

// Round 2
// 1633.536 us; speedup vs baseline: 1.6032x; 1.6032x over previous
//
#include <hip/hip_runtime.h>

// Billeh column GLIF forward — persistent kernel, fence-free grid barrier.
//
// Round-1 post-mortem: agent-scope fences/acquire-release on gfx950 emit full
// L2 writeback (buffer_wbl2) / invalidate (buffer_inv); the barrier poll loop
// invalidated L2 every iteration -> 2.5 ms of miss-latency stalls.
// This version uses ONLY relaxed per-access scoped atomics (cache-bypassing,
// MALL-coherent) for cross-block state, explicit s_waitcnt vmcnt(0) for
// store-completion ordering, and no fences anywhere. Read-only data stays in
// normal cached loads and is never invalidated.
//
// Structure: update-then-scatter with per-PRE-neuron CSR (built by 4 tiny
// setup kernels) and a double-buffered rec_in -> ONE grid barrier per step.

constexpr int RR = 4;

// ---------------------------------------------------------------- setup ----
__global__ void zero_kernel(float* p, size_t cnt, unsigned int* bar) {
    size_t i = blockIdx.x * (size_t)blockDim.x + threadIdx.x;
    size_t stride = (size_t)gridDim.x * blockDim.x;
    for (; i < cnt; i += stride) p[i] = 0.f;
    if (blockIdx.x == 0 && threadIdx.x == 0) *bar = 0u;
}

__global__ void hist_kernel(const int* __restrict__ pre, int* __restrict__ hist, int E) {
    int stride = gridDim.x * blockDim.x;
    for (int e = blockIdx.x * blockDim.x + threadIdx.x; e < E; e += stride)
        atomicAdd(&hist[pre[e]], 1);
}

// exclusive scan of hist within blocks of 1024; block totals to blocksum
__global__ void scan_kernel(const int* __restrict__ hist, int* __restrict__ loc,
                            int* __restrict__ blocksum, int N) {
    __shared__ int s[1024];
    int n = blockIdx.x * 1024 + threadIdx.x;
    int v = (n < N) ? hist[n] : 0;
    s[threadIdx.x] = v;
    __syncthreads();
    for (int off = 1; off < 1024; off <<= 1) {
        int t = (threadIdx.x >= (unsigned)off) ? s[threadIdx.x - off] : 0;
        __syncthreads();
        s[threadIdx.x] += t;
        __syncthreads();
    }
    if (n < N) loc[n] = s[threadIdx.x] - v;      // exclusive within block
    if (threadIdx.x == 1023) blocksum[blockIdx.x] = s[1023];
}

// exclusive scan of <=256 block sums (single block)
__global__ void topscan_kernel(const int* __restrict__ blocksum,
                               int* __restrict__ blockpref, int NB) {
    __shared__ int s[256];
    if (NB > 256) {                      // fallback (not hit at N=100000)
        if (threadIdx.x == 0) { int acc = 0; for (int b = 0; b < NB; b++) { blockpref[b] = acc; acc += blocksum[b]; } }
        return;
    }
    int v = ((int)threadIdx.x < NB) ? blocksum[threadIdx.x] : 0;
    s[threadIdx.x] = v;
    __syncthreads();
    for (int off = 1; off < 256; off <<= 1) {
        int t = (threadIdx.x >= (unsigned)off) ? s[threadIdx.x - off] : 0;
        __syncthreads();
        s[threadIdx.x] += t;
        __syncthreads();
    }
    if ((int)threadIdx.x < NB) blockpref[threadIdx.x] = s[threadIdx.x] - v;
}

// CSR fill: edges grouped by pre-neuron; payload = {slot = post*4+rc, w}
__global__ void fill_kernel(const int* __restrict__ pre, const int* __restrict__ post,
                            const int* __restrict__ rc, const float* __restrict__ w,
                            const int* __restrict__ loc, const int* __restrict__ blockpref,
                            int* __restrict__ cursor, uint2* __restrict__ edges, int E) {
    int stride = gridDim.x * blockDim.x;
    for (int e = blockIdx.x * blockDim.x + threadIdx.x; e < E; e += stride) {
        int p = pre[e];
        int base = blockpref[p >> 10] + loc[p];
        int k = atomicAdd(&cursor[p], 1);
        edges[base + k] = make_uint2((unsigned)(post[e] * RR + rc[e]),
                                     __float_as_uint(w[e]));
    }
}

// ------------------------------------------------------------ sim kernel ---
// Fence-free monotonic grid barrier: relaxed scoped atomics only. The explicit
// vmcnt(0) drain (all threads) guarantees this wave's MALL-coherent atomics
// and write-through stores have completed before arrival is flagged.
__device__ __forceinline__ void grid_barrier(unsigned int* bar, unsigned int target) {
    asm volatile("s_waitcnt vmcnt(0)" ::: "memory");
    __syncthreads();
    if (threadIdx.x == 0) {
        __hip_atomic_fetch_add(bar, 1u, __ATOMIC_RELAXED, __HIP_MEMORY_SCOPE_AGENT);
        while (__hip_atomic_load(bar, __ATOMIC_RELAXED, __HIP_MEMORY_SCOPE_AGENT) < target)
            __builtin_amdgcn_s_sleep(1);
    }
    __builtin_amdgcn_sched_barrier(0);
    __syncthreads();
}

__global__ void __launch_bounds__(256, 2)
sim_kernel(const float* __restrict__ x_ext,
           const float* __restrict__ v0,
           const float* __restrict__ v_th,
           const float* __restrict__ v_rst,
           const float* __restrict__ t_rf,
           const float* __restrict__ decay,
           const float* __restrict__ curf,
           const float* __restrict__ e_l,
           const float2* __restrict__ aamps,
           const float2* __restrict__ adec,
           const float* __restrict__ syn_d,
           const float* __restrict__ psc_i,
           const uint2* __restrict__ edges,
           const int* __restrict__ hist,
           const int* __restrict__ loc,
           const int* __restrict__ blockpref,
           float* __restrict__ recA,
           float* __restrict__ recB,
           unsigned int* __restrict__ bar,
           float* __restrict__ out,
           int N, int T)
{
    const int gtid = blockIdx.x * blockDim.x + threadIdx.x;
    const bool own = gtid < N;

    // ---- per-neuron state + params in registers for the whole run ----
    float psc0 = 0.f, psc1 = 0.f, psc2 = 0.f, psc3 = 0.f;
    float pr0 = 0.f, pr1 = 0.f, pr2 = 0.f, pr3 = 0.f;
    float vv = 0.f, rr = 0.f, zz = 0.f, a0 = 0.f, a1 = 0.f;
    float vth = 1.f, vrst = 0.f, trf = 0.f, dec = 0.f, cf = 0.f, el = 0.f;
    float aa0 = 0.f, aa1 = 0.f, ad0 = 0.f, ad1 = 0.f;
    int e_start = 0, e_end = 0;
    if (own) {
        vv  = v0[gtid];
        vth = v_th[gtid];  vrst = v_rst[gtid];
        trf = t_rf[gtid];  dec  = decay[gtid];
        cf  = curf[gtid];  el   = e_l[gtid];
        float2 aa = aamps[gtid]; aa0 = aa.x; aa1 = aa.y;
        float2 ad = adec[gtid];  ad0 = ad.x; ad1 = ad.y;
        e_start = blockpref[gtid >> 10] + loc[gtid];
        e_end   = e_start + hist[gtid];
    }
    const float sd0 = syn_d[0], sd1 = syn_d[1], sd2 = syn_d[2], sd3 = syn_d[3];
    const float pi0 = psc_i[0], pi1 = psc_i[1], pi2 = psc_i[2], pi3 = psc_i[3];

    const unsigned int nblk = gridDim.x;

    for (int t = 0; t < T; ++t) {
        float* R = (t & 1) ? recB : recA;   // read accumulated input
        float* W = (t & 1) ? recA : recB;   // scatter target for step t+1

        float nz = 0.f;
        if (own) {
            // coherent (MALL) read of own 4 slots, then restore zero invariant
            unsigned long long* rp = (unsigned long long*)(R + (size_t)4 * gtid);
            unsigned long long lo = __hip_atomic_load(rp,     __ATOMIC_RELAXED, __HIP_MEMORY_SCOPE_AGENT);
            unsigned long long hi = __hip_atomic_load(rp + 1, __ATOMIC_RELAXED, __HIP_MEMORY_SCOPE_AGENT);
            __hip_atomic_store(rp,     0ull, __ATOMIC_RELAXED, __HIP_MEMORY_SCOPE_AGENT);
            __hip_atomic_store(rp + 1, 0ull, __ATOMIC_RELAXED, __HIP_MEMORY_SCOPE_AGENT);
            float ri0 = __uint_as_float((unsigned)lo);
            float ri1 = __uint_as_float((unsigned)(lo >> 32));
            float ri2 = __uint_as_float((unsigned)hi);
            float ri3 = __uint_as_float((unsigned)(hi >> 32));

            float4 xt = ((const float4*)x_ext)[(size_t)t * N + gtid];
            float i0 = ri0 + xt.x, i1 = ri1 + xt.y, i2 = ri2 + xt.z, i3 = ri3 + xt.w;

            float npr0 = pr0 * sd0 + i0 * pi0;
            float npr1 = pr1 * sd1 + i1 * pi1;
            float npr2 = pr2 * sd2 + i2 * pi2;
            float npr3 = pr3 * sd3 + i3 * pi3;
            float npc0 = psc0 * sd0 + sd0 * pr0;   // OLD psc_rise, DT=1
            float npc1 = psc1 * sd1 + sd1 * pr1;
            float npc2 = psc2 * sd2 + sd2 * pr2;
            float npc3 = psc3 * sd3 + sd3 * pr3;
            float in_cur = npc0 + npc1 + npc2 + npc3;
            psc0 = npc0; psc1 = npc1; psc2 = npc2; psc3 = npc3;
            pr0 = npr0; pr1 = npr1; pr2 = npr2; pr3 = npr3;

            float asum = a0 + a1;                  // OLD asc sum
            a0 = ad0 * a0 + zz * aa0;
            a1 = ad1 * a1 + zz * aa1;

            float nv  = dec * vv + cf * (in_cur + asum + el) + zz * (vrst - vth);
            float vsc = (nv - vth) / vth;
            nz = (vsc > 0.f) ? 1.f : 0.f;
            if (rr > 0.f) nz = 0.f;                // refractory mask (OLD r)
            rr = fmaxf(rr - 1.f + nz * trf, 0.f);
            vv = nv; zz = nz;
            out[(size_t)t * N + gtid] = nz;        // normal cached store

            // ---- scatter own out-edges for step t+1 (only if spiked) ----
            if (nz > 0.f && t + 1 < T) {
                int j = e_start;
                for (; j + 1 < e_end; j += 2) {
                    uint2 ea = edges[j];
                    uint2 eb = edges[j + 1];
                    __hip_atomic_fetch_add(&W[ea.x], __uint_as_float(ea.y),
                                           __ATOMIC_RELAXED, __HIP_MEMORY_SCOPE_AGENT);
                    __hip_atomic_fetch_add(&W[eb.x], __uint_as_float(eb.y),
                                           __ATOMIC_RELAXED, __HIP_MEMORY_SCOPE_AGENT);
                }
                if (j < e_end) {
                    uint2 ea = edges[j];
                    __hip_atomic_fetch_add(&W[ea.x], __uint_as_float(ea.y),
                                           __ATOMIC_RELAXED, __HIP_MEMORY_SCOPE_AGENT);
                }
            }
        }

        if (t + 1 < T)
            grid_barrier(bar, (unsigned)(t + 1) * nblk);
    }
}

// ---------------------------------------------------------------- launch ---
extern "C" void kernel_launch(void* const* d_in, const int* in_sizes, int n_in,
                              void* d_out, int out_size, void* d_ws, size_t ws_size,
                              hipStream_t stream) {
    const float* w_rec = (const float*)d_in[0];
    const float* x_ext = (const float*)d_in[1];
    const float* v0    = (const float*)d_in[2];
    const float* v_th  = (const float*)d_in[3];
    const float* v_rst = (const float*)d_in[4];
    const float* t_rf  = (const float*)d_in[5];
    const float* decay = (const float*)d_in[6];
    const float* curf  = (const float*)d_in[7];
    const float* e_l   = (const float*)d_in[8];
    const float* aamps = (const float*)d_in[9];
    const float* adec  = (const float*)d_in[10];
    const float* syn_d = (const float*)d_in[11];
    const float* psc_i = (const float*)d_in[12];
    const int*   pre   = (const int*)d_in[13];
    const int*   post  = (const int*)d_in[14];
    const int*   rc    = (const int*)d_in[15];

    const int E = in_sizes[0];
    const int N = in_sizes[2];            // B == 1
    const int T = in_sizes[1] / (N * RR);
    const int NB = (N + 1023) / 1024;     // scan blocks of 1024

    // -------- workspace layout (edges first; everything 16B-aligned) --------
    uint2* edges     = (uint2*)d_ws;                       // E * 8B
    float* wf        = (float*)d_ws + (size_t)2 * E;
    float* recA      = wf;                                 // 4N
    float* recB      = recA + (size_t)4 * N;               // 4N
    int*   hist      = (int*)(recB + (size_t)4 * N);       // N
    int*   cursor    = hist + N;                           // N
    int*   loc       = cursor + N;                         // N
    int*   blocksum  = loc + N;                            // NB
    int*   blockpref = blocksum + NB;                      // NB
    unsigned int* bar = (unsigned int*)(blockpref + NB);   // 1

    // zero: recA, recB, hist, cursor (contiguous 10N words) + bar
    zero_kernel<<<1024, 256, 0, stream>>>(recA, (size_t)10 * N, bar);
    hist_kernel<<<2048, 256, 0, stream>>>(pre, hist, E);
    scan_kernel<<<NB, 1024, 0, stream>>>(hist, loc, blocksum, N);
    topscan_kernel<<<1, 256, 0, stream>>>(blocksum, blockpref, NB);
    fill_kernel<<<2048, 256, 0, stream>>>(pre, post, rc, w_rec, loc, blockpref,
                                          cursor, edges, E);

    const int BS = 256;
    const int nblk = (N + BS - 1) / BS;   // 391 blocks @ N=100000; co-residency
                                          // guaranteed: __launch_bounds__(256,2)
                                          // -> <=128 VGPR -> 2 blocks/CU -> 512 slots
    sim_kernel<<<nblk, BS, 0, stream>>>(
        x_ext, v0, v_th, v_rst, t_rf, decay, curf, e_l,
        (const float2*)aamps, (const float2*)adec, syn_d, psc_i,
        edges, hist, loc, blockpref, recA, recB, bar,
        (float*)d_out, N, T);
}